// Round 4
// baseline (363.837 us; speedup 1.0000x reference)
//
#include <hip/hip_runtime.h>
#include <hip/hip_bf16.h>
#include <math.h>

#define L 32768
#define C 256
#define QD 512
#define SCALE (1.0f/16.0f)

typedef __hip_bfloat16 bf16;
typedef short v8s __attribute__((ext_vector_type(8)));
typedef short v4s __attribute__((ext_vector_type(4)));
typedef float v4f __attribute__((ext_vector_type(4)));
typedef float v16f __attribute__((ext_vector_type(16)));
typedef int   v4i __attribute__((ext_vector_type(4)));

__device__ __forceinline__ void ldst16(void* lds, const void* g) {
    __builtin_amdgcn_global_load_lds(
        (const __attribute__((address_space(1))) unsigned int*)g,
        (__attribute__((address_space(3))) unsigned int*)lds, 16, 0, 0);
}
__device__ __forceinline__ short bfbits(float x) {
    bf16 h = __float2bfloat16(x);
    return *reinterpret_cast<short*>(&h);
}
__device__ __forceinline__ int cvtpk(float lo, float hi) {
    int d;
    asm("v_cvt_pk_bf16_f32 %0, %1, %2" : "=v"(d) : "v"(lo), "v"(hi));
    return d;
}
// exchanges hi-32-lanes of x with lo-32-lanes of y
__device__ __forceinline__ void pl32swap(int &x, int &y) {
    asm("v_permlane32_swap_b32 %0, %1" : "+v"(x), "+v"(y));
}

// ---------------------------------------------------------------------------
// prep: pack Wq/Wk/Wv -> Wall bf16 [768][512] (Wq pre-scaled by 1/16);
// Wo -> Wob bf16 [512][256]; biases -> ball fp32 [768] (bq pre-scaled).
// ---------------------------------------------------------------------------
__global__ __launch_bounds__(256) void prep(
    const float* __restrict__ Wq, const float* __restrict__ Wk,
    const float* __restrict__ Wv, const float* __restrict__ bq,
    const float* __restrict__ bk, const float* __restrict__ bv,
    const float* __restrict__ Wo,
    bf16* __restrict__ Wall, bf16* __restrict__ Wob, float* __restrict__ ball)
{
    int i = blockIdx.x * 256 + threadIdx.x;
    if (i < 768*512) {
        int row = i >> 9, idx = i & 511;
        const float* src = row < 256 ? Wq : row < 512 ? Wk : Wv;
        float v = src[(row & 255) * 512 + idx];
        if (row < 256) v *= SCALE;
        Wall[i] = __float2bfloat16(v);
    } else if (i < 768*512 + 512*256) {
        int j = i - 768*512;
        Wob[j] = __float2bfloat16(Wo[j]);
    } else if (i < 768*512 + 512*256 + 768) {
        int j = i - 768*512 - 512*256;
        ball[j] = j < 256 ? bq[j]*SCALE : j < 512 ? bk[j - 256] : bv[j - 512];
    }
}

// ---------------------------------------------------------------------------
// convt: x1 fp32 [512][L] -> x1T bf16 [L][512], 64x64 tiles via LDS.
// ---------------------------------------------------------------------------
__global__ __launch_bounds__(256) void convt(
    const float* __restrict__ x, short* __restrict__ xT)
{
    __shared__ short st[64*72];
    const int t = threadIdx.x;
    const int l0 = blockIdx.x * 64, c0 = blockIdx.y * 64;
    #pragma unroll
    for (int i = 0; i < 2; i++) {
        int v = i*256 + t;
        int c = v >> 3, l8 = (v & 7) << 3;
        const float* p = x + (size_t)(c0 + c) * L + l0 + l8;
        float4 f0 = *(const float4*)p;
        float4 f1 = *(const float4*)(p + 4);
        bf16* stb = (bf16*)st;
        stb[(l8+0)*72 + c] = __float2bfloat16(f0.x);
        stb[(l8+1)*72 + c] = __float2bfloat16(f0.y);
        stb[(l8+2)*72 + c] = __float2bfloat16(f0.z);
        stb[(l8+3)*72 + c] = __float2bfloat16(f0.w);
        stb[(l8+4)*72 + c] = __float2bfloat16(f1.x);
        stb[(l8+5)*72 + c] = __float2bfloat16(f1.y);
        stb[(l8+6)*72 + c] = __float2bfloat16(f1.z);
        stb[(l8+7)*72 + c] = __float2bfloat16(f1.w);
    }
    __syncthreads();
    #pragma unroll
    for (int i = 0; i < 2; i++) {
        int v = i*256 + t;
        int l = v >> 3, c8 = (v & 7) << 3;
        *(v8s*)(xT + (size_t)(l0 + l) * QD + c0 + c8) = *(const v8s*)&st[l*72 + c8];
    }
}

// ---------------------------------------------------------------------------
// Fused QKV GEMM (m97-style): Y[768][L] = Wall[768][512] . x1T[L][512]^T.
// ---------------------------------------------------------------------------
__global__ __launch_bounds__(256) void qkv_gemm(
    const bf16* __restrict__ A, const bf16* __restrict__ B,
    const float* __restrict__ ball,
    bf16* __restrict__ qT, bf16* __restrict__ kT, bf16* __restrict__ vB)
{
    __shared__ short sA[128*32];
    __shared__ short sB[128*32];
    __shared__ short sE[128*136];

    const int t    = threadIdx.x;
    const int lane = t & 63;
    const int w    = t >> 6;
    const int wm   = w & 1, wn = w >> 1;
    const int col  = lane & 15, quad = lane >> 4;
    const int n0   = blockIdx.x * 128;
    const int my   = blockIdx.y;
    const int m0   = my * 128;

    v4f acc[4][4];
    #pragma unroll
    for (int i = 0; i < 4; i++)
        #pragma unroll
        for (int j = 0; j < 4; j++) acc[i][j] = (v4f){0.f,0.f,0.f,0.f};

    for (int k0 = 0; k0 < QD; k0 += 32) {
        #pragma unroll
        for (int j = 0; j < 2; j++) {
            int idx = j*256 + t;
            int m = idx >> 2, k8 = (idx & 3) << 3;
            ldst16(&sA[idx*8], A + (size_t)(m0 + m) * QD + k0 + k8);
        }
        #pragma unroll
        for (int j = 0; j < 2; j++) {
            int idx = j*256 + t;
            int n = idx >> 2, k8 = (idx & 3) << 3;
            ldst16(&sB[idx*8], B + (size_t)(n0 + n) * QD + k0 + k8);
        }
        __syncthreads();
        v8s af[4], bf[4];
        #pragma unroll
        for (int mt = 0; mt < 4; mt++)
            af[mt] = *(const v8s*)&sA[(wm*64 + mt*16 + col)*32 + quad*8];
        #pragma unroll
        for (int nt = 0; nt < 4; nt++)
            bf[nt] = *(const v8s*)&sB[(wn*64 + nt*16 + col)*32 + quad*8];
        #pragma unroll
        for (int mt = 0; mt < 4; mt++)
            #pragma unroll
            for (int nt = 0; nt < 4; nt++)
                acc[mt][nt] = __builtin_amdgcn_mfma_f32_16x16x32_bf16(af[mt], bf[nt], acc[mt][nt], 0, 0, 0);
        __syncthreads();
    }

    float bias_v[4][4];
    #pragma unroll
    for (int mt = 0; mt < 4; mt++)
        #pragma unroll
        for (int r = 0; r < 4; r++)
            bias_v[mt][r] = ball[m0 + wm*64 + mt*16 + quad*4 + r];

    bf16* sEb = (bf16*)sE;
    if (my < 4) {
        #pragma unroll
        for (int mt = 0; mt < 4; mt++)
            #pragma unroll
            for (int nt = 0; nt < 4; nt++)
                #pragma unroll
                for (int r = 0; r < 4; r++)
                    sEb[(wn*64 + nt*16 + col)*136 + wm*64 + mt*16 + quad*4 + r] =
                        __float2bfloat16(acc[mt][nt][r] + bias_v[mt][r]);
        __syncthreads();
        bf16* dst = (my < 2) ? qT : kT;
        const int c0 = (my & 1) * 128;
        #pragma unroll
        for (int j = 0; j < 8; j++) {
            int idx = j*256 + t;
            int n = idx >> 4, c8 = (idx & 15) << 3;
            *(v8s*)(dst + (size_t)(n0 + n) * C + c0 + c8) = *(const v8s*)&sE[n*136 + c8];
        }
    } else {
        #pragma unroll
        for (int mt = 0; mt < 4; mt++)
            #pragma unroll
            for (int nt = 0; nt < 4; nt++)
                #pragma unroll
                for (int r = 0; r < 4; r++)
                    sEb[(wm*64 + mt*16 + quad*4 + r)*136 + wn*64 + nt*16 + col] =
                        __float2bfloat16(acc[mt][nt][r] + bias_v[mt][r]);
        __syncthreads();
        const int c0 = (my - 4) * 128;
        #pragma unroll
        for (int j = 0; j < 8; j++) {
            int idx = j*256 + t;
            int m = idx >> 4, n8 = (idx & 15) << 3;
            *(v8s*)(vB + (size_t)(c0 + m) * L + n0 + n8) = *(const v8s*)&sE[m*136 + n8];
        }
    }
}

// ---------------------------------------------------------------------------
// Output GEMM: out[512][L] = Wob[512][256].aoT[L][256]^T + bo, * mask.
// ---------------------------------------------------------------------------
__global__ __launch_bounds__(256) void out_gemm(
    const bf16* __restrict__ A, const bf16* __restrict__ B,
    const float* __restrict__ bo, const float* __restrict__ mask,
    float* __restrict__ out)
{
    __shared__ short sA[128*32];
    __shared__ short sB[128*32];
    __shared__ float sEf[64*132];

    const int t    = threadIdx.x;
    const int lane = t & 63;
    const int w    = t >> 6;
    const int wm   = w & 1, wn = w >> 1;
    const int col  = lane & 15, quad = lane >> 4;
    const int n0   = blockIdx.x * 128;
    const int m0   = blockIdx.y * 128;

    v4f acc[4][4];
    #pragma unroll
    for (int i = 0; i < 4; i++)
        #pragma unroll
        for (int j = 0; j < 4; j++) acc[i][j] = (v4f){0.f,0.f,0.f,0.f};

    for (int k0 = 0; k0 < C; k0 += 32) {
        #pragma unroll
        for (int j = 0; j < 2; j++) {
            int idx = j*256 + t;
            int m = idx >> 2, k8 = (idx & 3) << 3;
            ldst16(&sA[idx*8], A + (size_t)(m0 + m) * C + k0 + k8);
        }
        #pragma unroll
        for (int j = 0; j < 2; j++) {
            int idx = j*256 + t;
            int n = idx >> 2, k8 = (idx & 3) << 3;
            ldst16(&sB[idx*8], B + (size_t)(n0 + n) * C + k0 + k8);
        }
        __syncthreads();
        v8s af[4], bf[4];
        #pragma unroll
        for (int mt = 0; mt < 4; mt++)
            af[mt] = *(const v8s*)&sA[(wm*64 + mt*16 + col)*32 + quad*8];
        #pragma unroll
        for (int nt = 0; nt < 4; nt++)
            bf[nt] = *(const v8s*)&sB[(wn*64 + nt*16 + col)*32 + quad*8];
        #pragma unroll
        for (int mt = 0; mt < 4; mt++)
            #pragma unroll
            for (int nt = 0; nt < 4; nt++)
                acc[mt][nt] = __builtin_amdgcn_mfma_f32_16x16x32_bf16(af[mt], bf[nt], acc[mt][nt], 0, 0, 0);
        __syncthreads();
    }

    #pragma unroll
    for (int half = 0; half < 2; half++) {
        if (wm == half) {
            #pragma unroll
            for (int mt = 0; mt < 4; mt++) {
                #pragma unroll
                for (int r = 0; r < 4; r++) {
                    float bb = bo[m0 + half*64 + mt*16 + quad*4 + r];
                    #pragma unroll
                    for (int nt = 0; nt < 4; nt++)
                        sEf[(mt*16 + quad*4 + r)*132 + wn*64 + nt*16 + col] =
                            acc[mt][nt][r] + bb;
                }
            }
        }
        __syncthreads();
        #pragma unroll
        for (int j = 0; j < 8; j++) {
            int idx = j*256 + t;
            int row = idx >> 5, s4 = (idx & 31) << 2;
            float4 vv = *(const float4*)&sEf[row*132 + s4];
            float4 mk = *(const float4*)&mask[n0 + s4];
            vv.x *= mk.x; vv.y *= mk.y; vv.z *= mk.z; vv.w *= mk.w;
            *(float4*)&out[(size_t)(m0 + half*64 + row) * L + n0 + s4] = vv;
        }
        __syncthreads();
    }
}

// ---------------------------------------------------------------------------
// Flash sliding-window attention v8: 128q tile, 4 waves x 32q, 32x32x16 MFMA.
// r3 accounting: all pipes <=21% yet their serial SUM == the full period ->
// phase serialization. v8 attacks the serial sum: DS reads/q halved, VALU/q
// halved, 10 barrier periods (1 barrier each) vs 18(x2), mask loads -> bitmask
// precompute (also kills vmcnt-ordering hazard: consuming mask used to drain
// the K/V prefetch), SCALE folded into prep, defer-max skips O-rescale, P fed
// to PV in-register via cvt_pk_bf16 + permlane32_swap (T12 pattern).
// K/V staged by global_load_lds (no relay regs): K padded stride 264
// (row*33+s == linear slot), V XOR-swizzled (slot^=(row&7), pre-swizzled
// global source). LDS 130 KB dbuf, 1 block/CU, VGPR cap 512 (1 wave/SIMD).
// ---------------------------------------------------------------------------
__device__ __forceinline__ void stage_kv(
    const short* __restrict__ kT, const short* __restrict__ vB,
    int a0, int t, short* __restrict__ sK, short* __restrict__ sV)
{
    // K: 64 rows x 33 slots of 16B (slot 32 = pad). linear slot idx = row*33+s.
    #pragma unroll
    for (int i = 0; i < 9; i++) {
        int idx = i*256 + t;
        if (idx < 2112) {
            int row = idx / 33, s = idx % 33;
            int a  = min(max(a0 + row, 0), L - 1);
            int ss = min(s, 31);
            ldst16(&sK[idx*8], kT + (size_t)a * C + ss*8);
        }
    }
    // V: 256 rows x 8 slots of 16B, XOR-swizzle via pre-swizzled source.
    #pragma unroll
    for (int i = 0; i < 8; i++) {
        int idx = i*256 + t;
        int row = idx >> 3, s = idx & 7;
        int sl  = s ^ (row & 7);
        int ab  = min(max(a0 + sl*8, 0), L - 8);
        ldst16(&sV[idx*8], vB + (size_t)row * L + ab);
    }
}

__global__ __launch_bounds__(256, 1) void attn_mfma(
    const bf16* __restrict__ qT, const bf16* __restrict__ kT,
    const bf16* __restrict__ vB, const float* __restrict__ mask,
    bf16* __restrict__ aoT)
{
    __shared__ short sK [2][64*264];   // 2 x 33.0 KB
    __shared__ short sVt[2][256*64];   // 2 x 32.0 KB -> 130 KB total

    const int t    = threadIdx.x;   // 256 threads, 4 waves
    const int w    = t >> 6;
    const int lane = t & 63;
    const int l31  = lane & 31;
    const int hi   = lane >> 5;
    const int bx   = blockIdx.x;
    const int tile = ((bx & 7) << 5) | (bx >> 3);   // XCD-contiguous
    const int p0   = tile * 128;
    const int abase = p0 - 256;
    const int qg   = p0 + w*32 + l31;   // this lane's q row (col = l31)

    const short* kTs = (const short*)kT;
    const short* vBs = (const short*)vB;

    // stage chunk 0 first (oldest vmem ops)
    stage_kv(kTs, vBs, abase, t, sK[0], sVt[0]);

    // Q fragments (B operand): Q[qg][ks*16 + hi*8 + j], j=0..7
    v8s qf[16];
    {
        const short* qp = (const short*)qT + (size_t)qg * C + hi*8;
        #pragma unroll
        for (int ks = 0; ks < 16; ks++) qf[ks] = *(const v8s*)(qp + ks*16);
    }

    // validity bitmasks: bit (kt*16 + r) of mb[ch], key = a0+kt*32+4hi+8b+c,
    // r = 4b+c  (matches 32x32 C/D: row=(r&3)+8*(r>>2)+4*hi)
    unsigned mb[10];
    #pragma unroll
    for (int ch = 0; ch < 10; ch++) {
        unsigned m = 0;
        int a0 = abase + ch*64;
        #pragma unroll
        for (int kt = 0; kt < 2; kt++) {
            #pragma unroll
            for (int b = 0; b < 4; b++) {
                int a4 = a0 + kt*32 + b*8 + hi*4;
                int ac = min(max(a4, 0), L - 4);
                float4 mv = *(const float4*)&mask[ac];
                float mvv[4] = {mv.x, mv.y, mv.z, mv.w};
                #pragma unroll
                for (int c = 0; c < 4; c++) {
                    int a   = a4 + c;
                    int rel = a - qg + 256;
                    bool ok = ((unsigned)rel < 512u) &&
                              ((unsigned)a < (unsigned)L) && (mvv[c] > 0.f);
                    if (ok) m |= (1u << (kt*16 + b*4 + c));
                }
            }
        }
        mb[ch] = m;
    }

    v16f oacc[8];
    #pragma unroll
    for (int i = 0; i < 8; i++)
        #pragma unroll
        for (int j = 0; j < 16; j++) oacc[i][j] = 0.f;
    float mrow = -1e30f, lrow = 0.f;

    // per-lane V read offsets (shorts): slot = (2j+hi)^(l31&7), j=kt*2+mf
    int voff[4];
    #pragma unroll
    for (int j = 0; j < 4; j++) voff[j] = ((2*j + hi) ^ (l31 & 7)) * 8;

    __syncthreads();

    #pragma unroll
    for (int ch = 0; ch < 10; ch++) {
        const short* sKc = sK[ch & 1];
        const short* sVc = sVt[ch & 1];
        if (ch < 9)
            stage_kv(kTs, vBs, abase + (ch+1)*64, t, sK[(ch+1)&1], sVt[(ch+1)&1]);

        // ---- QK^T: A = K[key32 x k16], B = Q; D[key][q], q = l31 ----
        const short* kb = sKc + l31*264 + hi*8;
        v16f e[2];
        __builtin_amdgcn_s_setprio(1);
        #pragma unroll
        for (int kt = 0; kt < 2; kt++) {
            v16f acc;
            #pragma unroll
            for (int j = 0; j < 16; j++) acc[j] = 0.f;
            #pragma unroll
            for (int ks = 0; ks < 16; ks++) {
                v8s af = *(const v8s*)(kb + kt*8448 + ks*16);
                acc = __builtin_amdgcn_mfma_f32_32x32x16_bf16(af, qf[ks], acc, 0, 0, 0);
            }
            e[kt] = acc;
        }
        __builtin_amdgcn_s_setprio(0);

        // ---- mask + per-q max (q lane-local; hi-pair shares q) ----
        float cmax = -1e30f;
        #pragma unroll
        for (int kt = 0; kt < 2; kt++)
            #pragma unroll
            for (int r = 0; r < 16; r++) {
                bool ok = (mb[ch] >> (kt*16 + r)) & 1;
                float x = ok ? e[kt][r] : -1e30f;
                e[kt][r] = x;
                cmax = fmaxf(cmax, x);
            }
        cmax = fmaxf(cmax, __shfl_xor(cmax, 32));

        // ---- defer-max: rescale only when max grew past threshold ----
        if (cmax > mrow + 8.f) {
            float al = __expf(mrow - cmax);
            mrow = cmax;
            lrow *= al;
            #pragma unroll
            for (int i = 0; i < 8; i++)
                #pragma unroll
                for (int j = 0; j < 16; j++) oacc[i][j] *= al;
        }

        // ---- P = exp(E - m), row sum ----
        float psum = 0.f;
        #pragma unroll
        for (int kt = 0; kt < 2; kt++)
            #pragma unroll
            for (int r = 0; r < 16; r++) {
                float p = __expf(e[kt][r] - mrow);
                e[kt][r] = p;
                psum += p;
            }
        psum += __shfl_xor(psum, 32);
        lrow += psum;

        // ---- pack P -> B-fragments via cvt_pk + permlane32_swap ----
        // group(g): dwords X=(e[8g+0],e[8g+1]) Y=(2,3) U=(4,5) V=(6,7);
        // swap(X,U), swap(Y,V) -> frag = [X,Y,U,V] = P[k=hi*8+j][q]
        v8s pfr[2][2];
        #pragma unroll
        for (int kt = 0; kt < 2; kt++) {
            #pragma unroll
            for (int g = 0; g < 2; g++) {
                int X = cvtpk(e[kt][8*g+0], e[kt][8*g+1]);
                int Y = cvtpk(e[kt][8*g+2], e[kt][8*g+3]);
                int U = cvtpk(e[kt][8*g+4], e[kt][8*g+5]);
                int V = cvtpk(e[kt][8*g+6], e[kt][8*g+7]);
                pl32swap(X, U);
                pl32swap(Y, V);
                v4i d = (v4i){X, Y, U, V};
                pfr[kt][g] = *reinterpret_cast<v8s*>(&d);
            }
        }

        // ---- PV: A = V[ch32 x key16] from sVt (XOR slots), B = P frags ----
        const short* vb = sVc + l31*64;
        __builtin_amdgcn_s_setprio(1);
        #pragma unroll
        for (int cht = 0; cht < 8; cht++) {
            #pragma unroll
            for (int kt = 0; kt < 2; kt++) {
                #pragma unroll
                for (int mf = 0; mf < 2; mf++) {
                    v8s vf = *(const v8s*)(vb + cht*2048 + voff[kt*2 + mf]);
                    oacc[cht] = __builtin_amdgcn_mfma_f32_32x32x16_bf16(
                        vf, pfr[kt][mf], oacc[cht], 0, 0, 0);
                }
            }
        }
        __builtin_amdgcn_s_setprio(0);

        if (ch < 9) __syncthreads();
    }

    // ---- epilogue: lane-local normalize + ReLU; ch = cht*32 + 8b + 4hi + c
    float inv = (lrow > 0.f) ? 1.f / lrow : 0.f;
    short* aorow = (short*)aoT + (size_t)qg * C;
    #pragma unroll
    for (int cht = 0; cht < 8; cht++) {
        #pragma unroll
        for (int b = 0; b < 4; b++) {
            v4s pk;
            #pragma unroll
            for (int c = 0; c < 4; c++)
                pk[c] = bfbits(fmaxf(oacc[cht][b*4 + c] * inv, 0.f));
            *(v4s*)(aorow + cht*32 + b*8 + hi*4) = pk;
        }
    }
}

extern "C" void kernel_launch(void* const* d_in, const int* in_sizes, int n_in,
                              void* d_out, int out_size, void* d_ws, size_t ws_size,
                              hipStream_t stream)
{
    const float* x1   = (const float*)d_in[0];
    const float* mask = (const float*)d_in[2];
    const float* Wq   = (const float*)d_in[3];
    const float* bq   = (const float*)d_in[4];
    const float* Wk   = (const float*)d_in[5];
    const float* bk   = (const float*)d_in[6];
    const float* Wv   = (const float*)d_in[7];
    const float* bv   = (const float*)d_in[8];
    const float* Wo   = (const float*)d_in[9];
    const float* bo   = (const float*)d_in[10];
    float* out = (float*)d_out;

    bf16* x1T  = (bf16*)d_ws;
    bf16* Wall = x1T + (size_t)L * QD;
    bf16* Wob  = Wall + 768*512;
    float* ball = (float*)(Wob + 512*256);
    bf16* qT   = (bf16*)(ball + 768);
    bf16* kT   = qT + (size_t)L * C;
    bf16* vB   = kT + (size_t)L * C;
    bf16* aoT  = vB + (size_t)L * C;

    dim3 blk(256);
    prep<<<dim3((768*512 + 512*256 + 768 + 255)/256), blk, 0, stream>>>(
        Wq, Wk, Wv, bq, bk, bv, Wo, Wall, Wob, ball);
    convt<<<dim3(L/64, QD/64), blk, 0, stream>>>(x1, (short*)x1T);
    qkv_gemm<<<dim3(L/128, 6), blk, 0, stream>>>(Wall, x1T, ball, qT, kT, vB);
    attn_mfma<<<dim3(L/128), dim3(256), 0, stream>>>(qT, kT, vB, mask, aoT);
    out_gemm<<<dim3(L/128, 4), blk, 0, stream>>>(Wob, aoT, bo, mask, out);
}

// Round 6
// 354.604 us; speedup vs baseline: 1.0260x; 1.0260x over previous
//
#include <hip/hip_runtime.h>
#include <hip/hip_bf16.h>
#include <math.h>

#define L 32768
#define C 256
#define QD 512
#define SCALE (1.0f/16.0f)

typedef __hip_bfloat16 bf16;
typedef short v8s __attribute__((ext_vector_type(8)));
typedef short v4s __attribute__((ext_vector_type(4)));
typedef float v4f __attribute__((ext_vector_type(4)));
typedef float v16f __attribute__((ext_vector_type(16)));
typedef int   v4i __attribute__((ext_vector_type(4)));

__device__ __forceinline__ void ldst16(void* lds, const void* g) {
    __builtin_amdgcn_global_load_lds(
        (const __attribute__((address_space(1))) unsigned int*)g,
        (__attribute__((address_space(3))) unsigned int*)lds, 16, 0, 0);
}
__device__ __forceinline__ short bfbits(float x) {
    bf16 h = __float2bfloat16(x);
    return *reinterpret_cast<short*>(&h);
}
__device__ __forceinline__ int cvtpk(float lo, float hi) {
    int d;
    asm("v_cvt_pk_bf16_f32 %0, %1, %2" : "=v"(d) : "v"(lo), "v"(hi));
    return d;
}
// exchanges hi-32-lanes of x with lo-32-lanes of y
__device__ __forceinline__ void pl32swap(int &x, int &y) {
    asm("v_permlane32_swap_b32 %0, %1" : "+v"(x), "+v"(y));
}

// ---------------------------------------------------------------------------
// prep: pack Wq/Wk/Wv -> Wall bf16 [768][512] (Wq pre-scaled by 1/16);
// Wo -> Wob bf16 [512][256]; biases -> ball fp32 [768] (bq pre-scaled).
// ---------------------------------------------------------------------------
__global__ __launch_bounds__(256) void prep(
    const float* __restrict__ Wq, const float* __restrict__ Wk,
    const float* __restrict__ Wv, const float* __restrict__ bq,
    const float* __restrict__ bk, const float* __restrict__ bv,
    const float* __restrict__ Wo,
    bf16* __restrict__ Wall, bf16* __restrict__ Wob, float* __restrict__ ball)
{
    int i = blockIdx.x * 256 + threadIdx.x;
    if (i < 768*512) {
        int row = i >> 9, idx = i & 511;
        const float* src = row < 256 ? Wq : row < 512 ? Wk : Wv;
        float v = src[(row & 255) * 512 + idx];
        if (row < 256) v *= SCALE;
        Wall[i] = __float2bfloat16(v);
    } else if (i < 768*512 + 512*256) {
        int j = i - 768*512;
        Wob[j] = __float2bfloat16(Wo[j]);
    } else if (i < 768*512 + 512*256 + 768) {
        int j = i - 768*512 - 512*256;
        ball[j] = j < 256 ? bq[j]*SCALE : j < 512 ? bk[j - 256] : bv[j - 512];
    }
}

// ---------------------------------------------------------------------------
// convt: x1 fp32 [512][L] -> x1T bf16 [L][512], 64x64 tiles via LDS.
// ---------------------------------------------------------------------------
__global__ __launch_bounds__(256) void convt(
    const float* __restrict__ x, short* __restrict__ xT)
{
    __shared__ short st[64*72];
    const int t = threadIdx.x;
    const int l0 = blockIdx.x * 64, c0 = blockIdx.y * 64;
    #pragma unroll
    for (int i = 0; i < 2; i++) {
        int v = i*256 + t;
        int c = v >> 3, l8 = (v & 7) << 3;
        const float* p = x + (size_t)(c0 + c) * L + l0 + l8;
        float4 f0 = *(const float4*)p;
        float4 f1 = *(const float4*)(p + 4);
        bf16* stb = (bf16*)st;
        stb[(l8+0)*72 + c] = __float2bfloat16(f0.x);
        stb[(l8+1)*72 + c] = __float2bfloat16(f0.y);
        stb[(l8+2)*72 + c] = __float2bfloat16(f0.z);
        stb[(l8+3)*72 + c] = __float2bfloat16(f0.w);
        stb[(l8+4)*72 + c] = __float2bfloat16(f1.x);
        stb[(l8+5)*72 + c] = __float2bfloat16(f1.y);
        stb[(l8+6)*72 + c] = __float2bfloat16(f1.z);
        stb[(l8+7)*72 + c] = __float2bfloat16(f1.w);
    }
    __syncthreads();
    #pragma unroll
    for (int i = 0; i < 2; i++) {
        int v = i*256 + t;
        int l = v >> 3, c8 = (v & 7) << 3;
        *(v8s*)(xT + (size_t)(l0 + l) * QD + c0 + c8) = *(const v8s*)&st[l*72 + c8];
    }
}

// ---------------------------------------------------------------------------
// Fused QKV GEMM (m97-style): Y[768][L] = Wall[768][512] . x1T[L][512]^T.
// ---------------------------------------------------------------------------
__global__ __launch_bounds__(256) void qkv_gemm(
    const bf16* __restrict__ A, const bf16* __restrict__ B,
    const float* __restrict__ ball,
    bf16* __restrict__ qT, bf16* __restrict__ kT, bf16* __restrict__ vB)
{
    __shared__ short sA[128*32];
    __shared__ short sB[128*32];
    __shared__ short sE[128*136];

    const int t    = threadIdx.x;
    const int lane = t & 63;
    const int w    = t >> 6;
    const int wm   = w & 1, wn = w >> 1;
    const int col  = lane & 15, quad = lane >> 4;
    const int n0   = blockIdx.x * 128;
    const int my   = blockIdx.y;
    const int m0   = my * 128;

    v4f acc[4][4];
    #pragma unroll
    for (int i = 0; i < 4; i++)
        #pragma unroll
        for (int j = 0; j < 4; j++) acc[i][j] = (v4f){0.f,0.f,0.f,0.f};

    for (int k0 = 0; k0 < QD; k0 += 32) {
        #pragma unroll
        for (int j = 0; j < 2; j++) {
            int idx = j*256 + t;
            int m = idx >> 2, k8 = (idx & 3) << 3;
            ldst16(&sA[idx*8], A + (size_t)(m0 + m) * QD + k0 + k8);
        }
        #pragma unroll
        for (int j = 0; j < 2; j++) {
            int idx = j*256 + t;
            int n = idx >> 2, k8 = (idx & 3) << 3;
            ldst16(&sB[idx*8], B + (size_t)(n0 + n) * QD + k0 + k8);
        }
        __syncthreads();
        v8s af[4], bf[4];
        #pragma unroll
        for (int mt = 0; mt < 4; mt++)
            af[mt] = *(const v8s*)&sA[(wm*64 + mt*16 + col)*32 + quad*8];
        #pragma unroll
        for (int nt = 0; nt < 4; nt++)
            bf[nt] = *(const v8s*)&sB[(wn*64 + nt*16 + col)*32 + quad*8];
        #pragma unroll
        for (int mt = 0; mt < 4; mt++)
            #pragma unroll
            for (int nt = 0; nt < 4; nt++)
                acc[mt][nt] = __builtin_amdgcn_mfma_f32_16x16x32_bf16(af[mt], bf[nt], acc[mt][nt], 0, 0, 0);
        __syncthreads();
    }

    float bias_v[4][4];
    #pragma unroll
    for (int mt = 0; mt < 4; mt++)
        #pragma unroll
        for (int r = 0; r < 4; r++)
            bias_v[mt][r] = ball[m0 + wm*64 + mt*16 + quad*4 + r];

    bf16* sEb = (bf16*)sE;
    if (my < 4) {
        #pragma unroll
        for (int mt = 0; mt < 4; mt++)
            #pragma unroll
            for (int nt = 0; nt < 4; nt++)
                #pragma unroll
                for (int r = 0; r < 4; r++)
                    sEb[(wn*64 + nt*16 + col)*136 + wm*64 + mt*16 + quad*4 + r] =
                        __float2bfloat16(acc[mt][nt][r] + bias_v[mt][r]);
        __syncthreads();
        bf16* dst = (my < 2) ? qT : kT;
        const int c0 = (my & 1) * 128;
        #pragma unroll
        for (int j = 0; j < 8; j++) {
            int idx = j*256 + t;
            int n = idx >> 4, c8 = (idx & 15) << 3;
            *(v8s*)(dst + (size_t)(n0 + n) * C + c0 + c8) = *(const v8s*)&sE[n*136 + c8];
        }
    } else {
        #pragma unroll
        for (int mt = 0; mt < 4; mt++)
            #pragma unroll
            for (int nt = 0; nt < 4; nt++)
                #pragma unroll
                for (int r = 0; r < 4; r++)
                    sEb[(wm*64 + mt*16 + quad*4 + r)*136 + wn*64 + nt*16 + col] =
                        __float2bfloat16(acc[mt][nt][r] + bias_v[mt][r]);
        __syncthreads();
        const int c0 = (my - 4) * 128;
        #pragma unroll
        for (int j = 0; j < 8; j++) {
            int idx = j*256 + t;
            int m = idx >> 4, n8 = (idx & 15) << 3;
            *(v8s*)(vB + (size_t)(c0 + m) * L + n0 + n8) = *(const v8s*)&sE[m*136 + n8];
        }
    }
}

// ---------------------------------------------------------------------------
// Output GEMM: out[512][L] = Wob[512][256].aoT[L][256]^T + bo, * mask.
// ---------------------------------------------------------------------------
__global__ __launch_bounds__(256) void out_gemm(
    const bf16* __restrict__ A, const bf16* __restrict__ B,
    const float* __restrict__ bo, const float* __restrict__ mask,
    float* __restrict__ out)
{
    __shared__ short sA[128*32];
    __shared__ short sB[128*32];
    __shared__ float sEf[64*132];

    const int t    = threadIdx.x;
    const int lane = t & 63;
    const int w    = t >> 6;
    const int wm   = w & 1, wn = w >> 1;
    const int col  = lane & 15, quad = lane >> 4;
    const int n0   = blockIdx.x * 128;
    const int m0   = blockIdx.y * 128;

    v4f acc[4][4];
    #pragma unroll
    for (int i = 0; i < 4; i++)
        #pragma unroll
        for (int j = 0; j < 4; j++) acc[i][j] = (v4f){0.f,0.f,0.f,0.f};

    for (int k0 = 0; k0 < C; k0 += 32) {
        #pragma unroll
        for (int j = 0; j < 2; j++) {
            int idx = j*256 + t;
            int m = idx >> 2, k8 = (idx & 3) << 3;
            ldst16(&sA[idx*8], A + (size_t)(m0 + m) * C + k0 + k8);
        }
        #pragma unroll
        for (int j = 0; j < 2; j++) {
            int idx = j*256 + t;
            int n = idx >> 2, k8 = (idx & 3) << 3;
            ldst16(&sB[idx*8], B + (size_t)(n0 + n) * C + k0 + k8);
        }
        __syncthreads();
        v8s af[4], bf[4];
        #pragma unroll
        for (int mt = 0; mt < 4; mt++)
            af[mt] = *(const v8s*)&sA[(wm*64 + mt*16 + col)*32 + quad*8];
        #pragma unroll
        for (int nt = 0; nt < 4; nt++)
            bf[nt] = *(const v8s*)&sB[(wn*64 + nt*16 + col)*32 + quad*8];
        #pragma unroll
        for (int mt = 0; mt < 4; mt++)
            #pragma unroll
            for (int nt = 0; nt < 4; nt++)
                acc[mt][nt] = __builtin_amdgcn_mfma_f32_16x16x32_bf16(af[mt], bf[nt], acc[mt][nt], 0, 0, 0);
        __syncthreads();
    }

    #pragma unroll
    for (int half = 0; half < 2; half++) {
        if (wm == half) {
            #pragma unroll
            for (int mt = 0; mt < 4; mt++) {
                #pragma unroll
                for (int r = 0; r < 4; r++) {
                    float bb = bo[m0 + half*64 + mt*16 + quad*4 + r];
                    #pragma unroll
                    for (int nt = 0; nt < 4; nt++)
                        sEf[(mt*16 + quad*4 + r)*132 + wn*64 + nt*16 + col] =
                            acc[mt][nt][r] + bb;
                }
            }
        }
        __syncthreads();
        #pragma unroll
        for (int j = 0; j < 8; j++) {
            int idx = j*256 + t;
            int row = idx >> 5, s4 = (idx & 31) << 2;
            float4 vv = *(const float4*)&sEf[row*132 + s4];
            float4 mk = *(const float4*)&mask[n0 + s4];
            vv.x *= mk.x; vv.y *= mk.y; vv.z *= mk.z; vv.w *= mk.w;
            *(float4*)&out[(size_t)(m0 + half*64 + row) * L + n0 + s4] = vv;
        }
        __syncthreads();
    }
}

// ---------------------------------------------------------------------------
// Flash sliding-window attention v9 = v8 (verified numerics) minus the spill:
//  r4 post-mortem: VGPR demand ~290 vs 256 cap -> 79 MB scratch writes.
//  Fix 1: qf[16] (64 persistent VGPRs) -> per-chunk reload from global, base
//    laundered through asm volatile so LICM can't hoist the loads back into
//    loop-carried registers. Q loads are issued FIRST each chunk (oldest
//    vmem), so the counted vmcnt before QK^T completes them without draining
//    the K/V staging queued behind them.
//  Fix 2: per-kt (32-key subtile) softmax+PV -> E live range 16 regs not 32.
//    Exact same online-softmax algebra incl. defer-max zeroing of invalid
//    chunks (alpha=0 wipe, verified in r4).
//  Peak regs ~240 < 256. Everything else byte-identical to v8.
//  (Round 5 was an infra failure — container died before pytest; source
//   resubmitted unchanged to preserve attribution.)
// ---------------------------------------------------------------------------
__device__ __forceinline__ void stage_kv(
    const short* __restrict__ kT, const short* __restrict__ vB,
    int a0, int t, short* __restrict__ sK, short* __restrict__ sV)
{
    // K: 64 rows x 33 slots of 16B (slot 32 = pad). linear slot idx = row*33+s.
    #pragma unroll
    for (int i = 0; i < 9; i++) {
        int idx = i*256 + t;
        if (idx < 2112) {
            int row = idx / 33, s = idx % 33;
            int a  = min(max(a0 + row, 0), L - 1);
            int ss = min(s, 31);
            ldst16(&sK[idx*8], kT + (size_t)a * C + ss*8);
        }
    }
    // V: 256 rows x 8 slots of 16B, XOR-swizzle via pre-swizzled source.
    #pragma unroll
    for (int i = 0; i < 8; i++) {
        int idx = i*256 + t;
        int row = idx >> 3, s = idx & 7;
        int sl  = s ^ (row & 7);
        int ab  = min(max(a0 + sl*8, 0), L - 8);
        ldst16(&sV[idx*8], vB + (size_t)row * L + ab);
    }
}

__global__ __launch_bounds__(256, 1) void attn_mfma(
    const bf16* __restrict__ qT, const bf16* __restrict__ kT,
    const bf16* __restrict__ vB, const float* __restrict__ mask,
    bf16* __restrict__ aoT)
{
    __shared__ short sK [2][64*264];   // 2 x 33.0 KB
    __shared__ short sVt[2][256*64];   // 2 x 32.0 KB -> 130 KB total

    const int t    = threadIdx.x;   // 256 threads, 4 waves
    const int w    = t >> 6;
    const int lane = t & 63;
    const int l31  = lane & 31;
    const int hi   = lane >> 5;
    const int bx   = blockIdx.x;
    const int tile = ((bx & 7) << 5) | (bx >> 3);   // XCD-contiguous
    const int p0   = tile * 128;
    const int abase = p0 - 256;
    const int qg   = p0 + w*32 + l31;   // this lane's q row (col = l31)

    const short* kTs = (const short*)kT;
    const short* vBs = (const short*)vB;
    const short* qTs = (const short*)qT;

    // stage chunk 0 first (oldest vmem ops)
    stage_kv(kTs, vBs, abase, t, sK[0], sVt[0]);

    // validity bitmasks: bit (kt*16 + r) of mb[ch], key = a0+kt*32+4hi+8b+c,
    // r = 4b+c  (matches 32x32 C/D: row=(r&3)+8*(r>>2)+4*hi)
    unsigned mb[10];
    #pragma unroll
    for (int ch = 0; ch < 10; ch++) {
        unsigned m = 0;
        int a0 = abase + ch*64;
        #pragma unroll
        for (int kt = 0; kt < 2; kt++) {
            #pragma unroll
            for (int b = 0; b < 4; b++) {
                int a4 = a0 + kt*32 + b*8 + hi*4;
                int ac = min(max(a4, 0), L - 4);
                float4 mv = *(const float4*)&mask[ac];
                float mvv[4] = {mv.x, mv.y, mv.z, mv.w};
                #pragma unroll
                for (int c = 0; c < 4; c++) {
                    int a   = a4 + c;
                    int rel = a - qg + 256;
                    bool ok = ((unsigned)rel < 512u) &&
                              ((unsigned)a < (unsigned)L) && (mvv[c] > 0.f);
                    if (ok) m |= (1u << (kt*16 + b*4 + c));
                }
            }
        }
        mb[ch] = m;
    }

    v16f oacc[8];
    #pragma unroll
    for (int i = 0; i < 8; i++)
        #pragma unroll
        for (int j = 0; j < 16; j++) oacc[i][j] = 0.f;
    float mrow = -1e30f, lrow = 0.f;

    // per-lane V read offsets (shorts): slot = (2j+hi)^(l31&7), j=kt*2+mf
    int voff[4];
    #pragma unroll
    for (int j = 0; j < 4; j++) voff[j] = ((2*j + hi) ^ (l31 & 7)) * 8;

    __syncthreads();

    #pragma unroll
    for (int ch = 0; ch < 10; ch++) {
        const short* sKc = sK[ch & 1];
        const short* sVc = sVt[ch & 1];

        // ---- per-chunk Q reload (laundered base defeats LICM); issued
        //      BEFORE staging so Q loads are the oldest outstanding vmem ----
        int qoff = 0;
        asm volatile("" : "+v"(qoff));
        const short* qp = qTs + (size_t)qg * C + hi*8 + qoff;
        v8s qfr[16];
        #pragma unroll
        for (int ks = 0; ks < 16; ks++) qfr[ks] = *(const v8s*)(qp + ks*16);

        if (ch < 9)
            stage_kv(kTs, vBs, abase + (ch+1)*64, t, sK[(ch+1)&1], sVt[(ch+1)&1]);

        // ---- per-32-key subtile: QK^T -> softmax -> PV (E live = 16 regs) --
        #pragma unroll
        for (int kt = 0; kt < 2; kt++) {
            // QK^T: A = K[key32 x k16], B = Q; D[key][q], q = l31
            const short* kb = sKc + l31*264 + hi*8 + kt*8448;
            v16f e;
            #pragma unroll
            for (int j = 0; j < 16; j++) e[j] = 0.f;
            __builtin_amdgcn_s_setprio(1);
            #pragma unroll
            for (int ks = 0; ks < 16; ks++) {
                v8s af = *(const v8s*)(kb + ks*16);
                e = __builtin_amdgcn_mfma_f32_32x32x16_bf16(af, qfr[ks], e, 0, 0, 0);
            }
            __builtin_amdgcn_s_setprio(0);

            // mask + per-q max (q lane-local; hi-pair shares q)
            unsigned mbits = mb[ch] >> (kt*16);
            float cmax = -1e30f;
            #pragma unroll
            for (int r = 0; r < 16; r++) {
                bool ok = (mbits >> r) & 1;
                float x = ok ? e[r] : -1e30f;
                e[r] = x;
                cmax = fmaxf(cmax, x);
            }
            cmax = fmaxf(cmax, __shfl_xor(cmax, 32));

            // defer-max: rescale only when max grew past threshold.
            // invalid subtiles (cmax=-1e30) never trigger; first real
            // rescale's alpha=0 wipes their garbage (verified r4).
            if (cmax > mrow + 8.f) {
                float al = __expf(mrow - cmax);
                mrow = cmax;
                lrow *= al;
                #pragma unroll
                for (int i = 0; i < 8; i++)
                    #pragma unroll
                    for (int j = 0; j < 16; j++) oacc[i][j] *= al;
            }

            // P = exp(E - m), row sum
            float psum = 0.f;
            #pragma unroll
            for (int r = 0; r < 16; r++) {
                float p = __expf(e[r] - mrow);
                e[r] = p;
                psum += p;
            }
            psum += __shfl_xor(psum, 32);
            lrow += psum;

            // pack P -> B-fragments via cvt_pk + permlane32_swap
            v8s pfr[2];
            #pragma unroll
            for (int g = 0; g < 2; g++) {
                int X = cvtpk(e[8*g+0], e[8*g+1]);
                int Y = cvtpk(e[8*g+2], e[8*g+3]);
                int U = cvtpk(e[8*g+4], e[8*g+5]);
                int V = cvtpk(e[8*g+6], e[8*g+7]);
                pl32swap(X, U);
                pl32swap(Y, V);
                v4i d = (v4i){X, Y, U, V};
                pfr[g] = *reinterpret_cast<v8s*>(&d);
            }

            // PV for this key-half: A = V[ch32 x key16] (XOR slots), B = P
            const short* vb = sVc + l31*64;
            __builtin_amdgcn_s_setprio(1);
            #pragma unroll
            for (int cht = 0; cht < 8; cht++) {
                #pragma unroll
                for (int mf = 0; mf < 2; mf++) {
                    v8s vf = *(const v8s*)(vb + cht*2048 + voff[kt*2 + mf]);
                    oacc[cht] = __builtin_amdgcn_mfma_f32_32x32x16_bf16(
                        vf, pfr[mf], oacc[cht], 0, 0, 0);
                }
            }
            __builtin_amdgcn_s_setprio(0);
        }

        if (ch < 9) __syncthreads();
    }

    // ---- epilogue: lane-local normalize + ReLU; ch = cht*32 + 8b + 4hi + c
    float inv = (lrow > 0.f) ? 1.f / lrow : 0.f;
    short* aorow = (short*)aoT + (size_t)qg * C;
    #pragma unroll
    for (int cht = 0; cht < 8; cht++) {
        #pragma unroll
        for (int b = 0; b < 4; b++) {
            v4s pk;
            #pragma unroll
            for (int c = 0; c < 4; c++)
                pk[c] = bfbits(fmaxf(oacc[cht][b*4 + c] * inv, 0.f));
            *(v4s*)(aorow + cht*32 + b*8 + hi*4) = pk;
        }
    }
}

extern "C" void kernel_launch(void* const* d_in, const int* in_sizes, int n_in,
                              void* d_out, int out_size, void* d_ws, size_t ws_size,
                              hipStream_t stream)
{
    const float* x1   = (const float*)d_in[0];
    const float* mask = (const float*)d_in[2];
    const float* Wq   = (const float*)d_in[3];
    const float* bq   = (const float*)d_in[4];
    const float* Wk   = (const float*)d_in[5];
    const float* bk   = (const float*)d_in[6];
    const float* Wv   = (const float*)d_in[7];
    const float* bv   = (const float*)d_in[8];
    const float* Wo   = (const float*)d_in[9];
    const float* bo   = (const float*)d_in[10];
    float* out = (float*)d_out;

    bf16* x1T  = (bf16*)d_ws;
    bf16* Wall = x1T + (size_t)L * QD;
    bf16* Wob  = Wall + 768*512;
    float* ball = (float*)(Wob + 512*256);
    bf16* qT   = (bf16*)(ball + 768);
    bf16* kT   = qT + (size_t)L * C;
    bf16* vB   = kT + (size_t)L * C;
    bf16* aoT  = vB + (size_t)L * C;

    dim3 blk(256);
    prep<<<dim3((768*512 + 512*256 + 768 + 255)/256), blk, 0, stream>>>(
        Wq, Wk, Wv, bq, bk, bv, Wo, Wall, Wob, ball);
    convt<<<dim3(L/64, QD/64), blk, 0, stream>>>(x1, (short*)x1T);
    qkv_gemm<<<dim3(L/128, 6), blk, 0, stream>>>(Wall, x1T, ball, qT, kT, vB);
    attn_mfma<<<dim3(L/128), dim3(256), 0, stream>>>(qT, kT, vB, mask, aoT);
    out_gemm<<<dim3(L/128, 4), blk, 0, stream>>>(Wob, aoT, bo, mask, out);
}